// Round 11
// baseline (145.053 us; speedup 1.0000x reference)
//
#include <hip/hip_runtime.h>

#define NN 16384
#define EE 262144
#define TT 4
#define DD 64
#define SLOT 96          // slots per node; P(deg>96)~e^-100 for Poisson(16)
#define HB (EE / 256)    // edge-build blocks
#define NB (NN / 64)     // node0 tile blocks
#define WPAD 100         // padded edge-table stride (100 % 32 == 4 -> conflict-free)

__device__ inline float wave_reduce_sum(float v) {
    #pragma unroll
    for (int off = 32; off >= 1; off >>= 1) v += __shfl_xor(v, off);
    return v;
}
__device__ inline unsigned short f2bf(float f) {   // RNE
    unsigned u = __float_as_uint(f);
    u += 0x7FFFu + ((u >> 16) & 1u);
    return (unsigned short)(u >> 16);
}
__device__ inline float bf2f(unsigned short h) {
    return __uint_as_float(((unsigned)h) << 16);
}
__device__ inline float4 bf4_to_f4(ushort4 h) {
    return float4{bf2f(h.x), bf2f(h.y), bf2f(h.z), bf2f(h.w)};
}
__device__ inline ushort4 f4_to_bf4(float4 f) {
    return ushort4{f2bf(f.x), f2bf(f.y), f2bf(f.z), f2bf(f.w)};
}
// exp with clamp: softmax is shift-invariant; |rp| <~ 10 here so clamp is
// never active in practice, it only guarantees no inf/NaN.
__device__ inline float cexp(float r) {
    return __expf(fminf(fmaxf(r, -60.f), 60.f));
}

// ---- Fused: slot-CSR build + node0 GEMM tiles + small tables ------------
__global__ __launch_bounds__(256) void build_node0_kernel(
        const int* __restrict__ row, const int* __restrict__ col,
        const int* __restrict__ et, int* __restrict__ cnt,
        int* __restrict__ ce_slot,
        const float* __restrict__ x, const float* __restrict__ theta,
        const float* __restrict__ we, const float* __restrict__ ef_in,
        const float* __restrict__ wr,
        float* __restrict__ a4, float* __restrict__ b4,
        unsigned short* __restrict__ hw0,
        float* __restrict__ sg, float* __restrict__ rg) {
    __shared__ float h_lds[64][68];
    __shared__ float4 we_lds[64][16];
    __shared__ float th_lds[4][2][64];
    __shared__ float part_a[64][4][4];
    __shared__ float part_b[64][4][4];
    __shared__ float ef0[TT * DD];
    __shared__ float ef1[TT * DD];
    int tid = threadIdx.x;
    int bid = blockIdx.x;

    if (bid < HB) {                      // ---- hist+scatter in one pass
        int e = bid * 256 + tid;
        int r = row[e];
        int pos = atomicAdd(&cnt[r], 1);
        if (pos < SLOT)                  // clamp: never corrupt memory
            ce_slot[r * SLOT + pos] = col[e] | (et[e] << 14);
        return;
    }
    bid -= HB;

    if (bid == NB) {                     // ---- small tables (both layers)
        int t = tid >> 6, d = tid & 63;
        ef0[tid] = ef_in[tid];
        __syncthreads();
        if (tid < 16) {
            int tt = tid & 3, tq = tid >> 2;
            float s = 0.f;
            for (int k = 0; k < DD; ++k) s += theta[tq * 192 + k] * ef0[tt * DD + k];
            rg[tq * 4 + tt] = s;
        }
        float acc = 0.f;
        for (int k = 0; k < DD; ++k) acc += ef0[t * DD + k] * wr[k * DD + d];
        sg[tid] = 1.f / (1.f + __expf(-acc));
        ef1[tid] = fmaxf(acc, 0.f);
        __syncthreads();
        if (tid < 16) {
            int tt = tid & 3, tq = tid >> 2;
            float s = 0.f;
            for (int k = 0; k < DD; ++k) s += theta[(TT + tq) * 192 + k] * ef1[tt * DD + k];
            rg[16 + tq * 4 + tt] = s;
        }
        float acc2 = 0.f;
        for (int k = 0; k < DD; ++k) acc2 += ef1[t * DD + k] * wr[DD * DD + k * DD + d];
        sg[TT * DD + tid] = 1.f / (1.f + __expf(-acc2));
        return;
    }

    // ---- node0 tile: x@we0 -> hw0 (bf16), packed a4,b4 for all 4 t
    int n0 = bid * 64;
    {
        int q = tid & 15, nr = tid >> 4;
        #pragma unroll
        for (int r = 0; r < 4; ++r) {
            int n = r * 16 + nr;
            *(float4*)&h_lds[n][4 * q] = ((const float4*)x)[(n0 + n) * 16 + q];
        }
    }
    {
        const float4* we4 = (const float4*)we;
        #pragma unroll
        for (int r = 0; r < 4; ++r)
            ((float4*)we_lds)[tid + 256 * r] = we4[tid + 256 * r];
    }
    {
        #pragma unroll
        for (int r = 0; r < 2; ++r) {
            int e = tid + 256 * r;
            int t = e >> 7, ab = (e >> 6) & 1, k = e & 63;
            th_lds[t][ab][k] = theta[t * 192 + 64 + ab * 64 + k];
        }
    }
    __syncthreads();
    int i = tid >> 4, j = tid & 15;
    float4 acc[4];
    acc[0] = acc[1] = acc[2] = acc[3] = float4{0.f, 0.f, 0.f, 0.f};
    for (int k = 0; k < 64; ++k) {
        float4 wv = we_lds[k][j];
        #pragma unroll
        for (int r = 0; r < 4; ++r) {
            float hv = h_lds[4 * i + r][k];
            acc[r].x += hv * wv.x; acc[r].y += hv * wv.y;
            acc[r].z += hv * wv.z; acc[r].w += hv * wv.w;
        }
    }
    {   // a,b partials: thread j -> (t = j>>2, k range [16*(j&3), +16))
        int t = j >> 2, kq = j & 3;
        float pa[4] = {0, 0, 0, 0}, pb[4] = {0, 0, 0, 0};
        for (int kk = 0; kk < 16; ++kk) {
            int k = kq * 16 + kk;
            float ti = th_lds[t][0][k], tj = th_lds[t][1][k];
            #pragma unroll
            for (int r = 0; r < 4; ++r) {
                float hv = h_lds[4 * i + r][k];
                pa[r] += hv * ti; pb[r] += hv * tj;
            }
        }
        #pragma unroll
        for (int r = 0; r < 4; ++r) {
            part_a[4 * i + r][t][kq] = pa[r];
            part_b[4 * i + r][t][kq] = pb[r];
        }
    }
    #pragma unroll
    for (int r = 0; r < 4; ++r)
        ((ushort4*)hw0)[(n0 + 4 * i + r) * 16 + j] = f4_to_bf4(acc[r]);
    __syncthreads();
    {
        int n = tid >> 2, t = tid & 3;
        float4 va = *(float4*)&part_a[n][t][0];
        float4 vb = *(float4*)&part_b[n][t][0];
        a4[(n0 + n) * 4 + t] = va.x + va.y + va.z + va.w;
        b4[(n0 + n) * 4 + t] = vb.x + vb.y + vb.z + vb.w;
    }
}

// ---- Layer-1 node transforms: per-t tiled GEMM h1(bf16)@we1 -------------
// hw1 written INTERLEAVED: [n][t][d] so agg1 reads 512 contiguous B/edge.
__global__ __launch_bounds__(256) void node1_kernel(
        const unsigned short* __restrict__ h1, const float* __restrict__ theta,
        const float* __restrict__ we,
        float* __restrict__ a4, float* __restrict__ b4,
        unsigned short* __restrict__ hw) {
    __shared__ float h_lds[64][68];
    __shared__ float4 we_lds[64][16];
    __shared__ float th_lds[2][64];
    __shared__ float part_a[64][17];
    __shared__ float part_b[64][17];
    int tid = threadIdx.x;
    int t = blockIdx.y;
    int n0 = blockIdx.x * 64;
    const ushort4* ht = (const ushort4*)h1 + (size_t)t * NN * 16;
    {
        int q = tid & 15, nr = tid >> 4;
        #pragma unroll
        for (int r = 0; r < 4; ++r) {
            int n = r * 16 + nr;
            *(float4*)&h_lds[n][4 * q] = bf4_to_f4(ht[(n0 + n) * 16 + q]);
        }
    }
    {
        const float4* we4 = (const float4*)(we + DD * DD);
        #pragma unroll
        for (int r = 0; r < 4; ++r)
            ((float4*)we_lds)[tid + 256 * r] = we4[tid + 256 * r];
    }
    if (tid < 128) {
        int ab = tid >> 6, k = tid & 63;
        th_lds[ab][k] = theta[(TT + t) * 192 + 64 + ab * 64 + k];
    }
    __syncthreads();
    int i = tid >> 4, j = tid & 15;
    float4 acc[4];
    acc[0] = acc[1] = acc[2] = acc[3] = float4{0.f, 0.f, 0.f, 0.f};
    for (int k = 0; k < 64; ++k) {
        float4 wv = we_lds[k][j];
        #pragma unroll
        for (int r = 0; r < 4; ++r) {
            float hv = h_lds[4 * i + r][k];
            acc[r].x += hv * wv.x; acc[r].y += hv * wv.y;
            acc[r].z += hv * wv.z; acc[r].w += hv * wv.w;
        }
    }
    {   // a,b partials: thread j covers k in [4j, 4j+4)
        float pa[4] = {0, 0, 0, 0}, pb[4] = {0, 0, 0, 0};
        #pragma unroll
        for (int kk = 0; kk < 4; ++kk) {
            int k = 4 * j + kk;
            float ti = th_lds[0][k], tj = th_lds[1][k];
            #pragma unroll
            for (int r = 0; r < 4; ++r) {
                float hv = h_lds[4 * i + r][k];
                pa[r] += hv * ti; pb[r] += hv * tj;
            }
        }
        #pragma unroll
        for (int r = 0; r < 4; ++r) {
            part_a[4 * i + r][j] = pa[r];
            part_b[4 * i + r][j] = pb[r];
        }
    }
    #pragma unroll
    for (int r = 0; r < 4; ++r)
        ((ushort4*)hw)[(size_t)(n0 + 4 * i + r) * 64 + t * 16 + j] = f4_to_bf4(acc[r]);
    __syncthreads();
    if (tid < 64) {
        float s = 0.f;
        #pragma unroll
        for (int jj = 0; jj < 16; ++jj) s += part_a[tid][jj];
        a4[(n0 + tid) * 4 + t] = s;
    } else if (tid < 128) {
        int n = tid - 64;
        float s = 0.f;
        #pragma unroll
        for (int jj = 0; jj < 16; ++jj) s += part_b[n][jj];
        b4[(n0 + n) * 4 + t] = s;
    }
}

// ---- Layer-0 edge agg: plane-per-group, x2-unrolled gather loop ---------
__global__ __launch_bounds__(256) void edge_agg0_kernel(
        const int* __restrict__ cnt, const int* __restrict__ ce_slot,
        const float* __restrict__ a4, const float* __restrict__ b4,
        const float* __restrict__ rg, const float* __restrict__ sg,
        const unsigned short* __restrict__ hw0, unsigned short* __restrict__ h1) {
    __shared__ float4 sg4[64];
    __shared__ float4 rg4[4];
    __shared__ int   pkS[4][WPAD];
    __shared__ float wS[4][4][WPAD];
    int tid = threadIdx.x;
    if (tid < 64) sg4[tid] = ((const float4*)sg)[tid];
    if (tid < 4)  rg4[tid] = float4{rg[tid], rg[4 + tid], rg[8 + tid], rg[12 + tid]};
    int w = tid >> 6, lane = tid & 63;
    int n = blockIdx.x * 4 + w;
    int deg = cnt[n]; if (deg > SLOT) deg = SLOT;
    const int* ces = ce_slot + n * SLOT;
    float4 av = ((const float4*)a4)[n];
    __syncthreads();

    // Phase A: lane-per-edge, unnormalized exp weights (no max reduction)
    bool ok1 = lane < deg;
    int pk1 = ok1 ? ces[lane] : 0;
    int c1 = pk1 & 16383, tt1 = pk1 >> 14;
    float4 bv = ((const float4*)b4)[c1];
    float4 rv = rg4[tt1];
    float4 w1;
    w1.x = ok1 ? cexp(av.x + bv.x + rv.x) : 0.f;
    w1.y = ok1 ? cexp(av.y + bv.y + rv.y) : 0.f;
    w1.z = ok1 ? cexp(av.z + bv.z + rv.z) : 0.f;
    w1.w = ok1 ? cexp(av.w + bv.w + rv.w) : 0.f;
    pkS[w][lane] = pk1;
    wS[w][0][lane] = w1.x; wS[w][1][lane] = w1.y;
    wS[w][2][lane] = w1.z; wS[w][3][lane] = w1.w;
    float4 w2{0.f, 0.f, 0.f, 0.f};
    if (deg > 64) {                      // wave-uniform, ~never taken
        bool ok2 = lane + 64 < deg;
        int pk2 = ok2 ? ces[lane + 64] : 0;
        int c2 = pk2 & 16383, tt2 = pk2 >> 14;
        float4 bv2 = ((const float4*)b4)[c2];
        float4 rv2 = rg4[tt2];
        w2.x = ok2 ? cexp(av.x + bv2.x + rv2.x) : 0.f;
        w2.y = ok2 ? cexp(av.y + bv2.y + rv2.y) : 0.f;
        w2.z = ok2 ? cexp(av.z + bv2.z + rv2.z) : 0.f;
        w2.w = ok2 ? cexp(av.w + bv2.w + rv2.w) : 0.f;
        if (lane < WPAD - 64) {
            pkS[w][64 + lane] = pk2;
            wS[w][0][64 + lane] = w2.x; wS[w][1][64 + lane] = w2.y;
            wS[w][2][64 + lane] = w2.z; wS[w][3][64 + lane] = w2.w;
        }
    }
    // same-wave LDS write->read: no barrier needed

    // Phase B: group eg owns t-plane eg; all groups read the SAME hw0 line
    // per edge (coalescer dedups) -> no cross-group reduce tail.
    int eg = lane >> 4, q = lane & 15;
    float4 accA{0, 0, 0, 0}, accB{0, 0, 0, 0};
    const ushort4* hw4 = (const ushort4*)hw0;
    int e = 0;
    for (; e + 2 <= deg; e += 2) {
        int pkA = pkS[w][e], pkB = pkS[w][e + 1];
        int cA = pkA & 16383, ttA = pkA >> 14;
        int cB = pkB & 16383, ttB = pkB >> 14;
        ushort4 hA = hw4[cA * 16 + q];
        ushort4 hB = hw4[cB * 16 + q];
        float wA = wS[w][eg][e], wB = wS[w][eg][e + 1];
        float4 sA = sg4[ttA * 16 + q], sB = sg4[ttB * 16 + q];
        float4 fA = bf4_to_f4(hA), fB = bf4_to_f4(hB);
        accA.x += wA * (sA.x * fA.x); accA.y += wA * (sA.y * fA.y);
        accA.z += wA * (sA.z * fA.z); accA.w += wA * (sA.w * fA.w);
        accB.x += wB * (sB.x * fB.x); accB.y += wB * (sB.y * fB.y);
        accB.z += wB * (sB.z * fB.z); accB.w += wB * (sB.w * fB.w);
    }
    if (e < deg) {
        int pk = pkS[w][e];
        int c = pk & 16383, tt = pk >> 14;
        ushort4 hv = hw4[c * 16 + q];
        float wv = wS[w][eg][e];
        float4 sv = sg4[tt * 16 + q];
        float4 f = bf4_to_f4(hv);
        accA.x += wv * (sv.x * f.x); accA.y += wv * (sv.y * f.y);
        accA.z += wv * (sv.z * f.z); accA.w += wv * (sv.w * f.w);
    }
    float S0 = wave_reduce_sum(w1.x + w2.x);
    float S1 = wave_reduce_sum(w1.y + w2.y);
    float S2 = wave_reduce_sum(w1.z + w2.z);
    float S3 = wave_reduce_sum(w1.w + w2.w);
    float i0 = (S0 > 0.f) ? 1.f / S0 : 0.f, i1 = (S1 > 0.f) ? 1.f / S1 : 0.f;
    float i2 = (S2 > 0.f) ? 1.f / S2 : 0.f, i3 = (S3 > 0.f) ? 1.f / S3 : 0.f;
    float is = (eg == 0) ? i0 : (eg == 1) ? i1 : (eg == 2) ? i2 : i3;
    float4 o{(accA.x + accB.x) * is, (accA.y + accB.y) * is,
             (accA.z + accB.z) * is, (accA.w + accB.w) * is};
    o.x = fmaxf(o.x, 0.f); o.y = fmaxf(o.y, 0.f);
    o.z = fmaxf(o.z, 0.f); o.w = fmaxf(o.w, 0.f);
    ((ushort4*)h1)[(eg * NN + n) * 16 + q] = f4_to_bf4(o);   // bf16 h1
}

// ---- Layer-1 edge agg: plane-per-group, x2-unrolled, 512B/edge ----------
__global__ __launch_bounds__(256) void edge_agg1_kernel(
        const int* __restrict__ cnt, const int* __restrict__ ce_slot,
        const float* __restrict__ a4, const float* __restrict__ b4,
        const float* __restrict__ rg, const float* __restrict__ sg,
        const unsigned short* __restrict__ hw, float* __restrict__ out) {
    __shared__ float4 sg4[64];
    __shared__ float4 rg4[4];
    __shared__ int   pkS[4][WPAD];
    __shared__ float wS[4][4][WPAD];
    int tid = threadIdx.x;
    if (tid < 64) sg4[tid] = ((const float4*)sg)[tid];
    if (tid < 4)  rg4[tid] = float4{rg[tid], rg[4 + tid], rg[8 + tid], rg[12 + tid]};
    int w = tid >> 6, lane = tid & 63;
    int n = blockIdx.x * 4 + w;
    int deg = cnt[n]; if (deg > SLOT) deg = SLOT;
    const int* ces = ce_slot + n * SLOT;
    float4 av = ((const float4*)a4)[n];
    __syncthreads();

    // Phase A (identical to agg0)
    bool ok1 = lane < deg;
    int pk1 = ok1 ? ces[lane] : 0;
    int c1 = pk1 & 16383, tt1 = pk1 >> 14;
    float4 bv = ((const float4*)b4)[c1];
    float4 rv = rg4[tt1];
    float4 w1;
    w1.x = ok1 ? cexp(av.x + bv.x + rv.x) : 0.f;
    w1.y = ok1 ? cexp(av.y + bv.y + rv.y) : 0.f;
    w1.z = ok1 ? cexp(av.z + bv.z + rv.z) : 0.f;
    w1.w = ok1 ? cexp(av.w + bv.w + rv.w) : 0.f;
    pkS[w][lane] = pk1;
    wS[w][0][lane] = w1.x; wS[w][1][lane] = w1.y;
    wS[w][2][lane] = w1.z; wS[w][3][lane] = w1.w;
    float4 w2{0.f, 0.f, 0.f, 0.f};
    if (deg > 64) {                      // wave-uniform, ~never taken
        bool ok2 = lane + 64 < deg;
        int pk2 = ok2 ? ces[lane + 64] : 0;
        int c2 = pk2 & 16383, tt2 = pk2 >> 14;
        float4 bv2 = ((const float4*)b4)[c2];
        float4 rv2 = rg4[tt2];
        w2.x = ok2 ? cexp(av.x + bv2.x + rv2.x) : 0.f;
        w2.y = ok2 ? cexp(av.y + bv2.y + rv2.y) : 0.f;
        w2.z = ok2 ? cexp(av.z + bv2.z + rv2.z) : 0.f;
        w2.w = ok2 ? cexp(av.w + bv2.w + rv2.w) : 0.f;
        if (lane < WPAD - 64) {
            pkS[w][64 + lane] = pk2;
            wS[w][0][64 + lane] = w2.x; wS[w][1][64 + lane] = w2.y;
            wS[w][2][64 + lane] = w2.z; wS[w][3][64 + lane] = w2.w;
        }
    }

    // Phase B: group eg owns t-plane eg; 512 contiguous B per edge.
    int eg = lane >> 4, q = lane & 15;
    float4 accA{0, 0, 0, 0}, accB{0, 0, 0, 0};
    const ushort4* hw4 = (const ushort4*)hw;
    int e = 0;
    for (; e + 2 <= deg; e += 2) {
        int pkA = pkS[w][e], pkB = pkS[w][e + 1];
        int cA = pkA & 16383, ttA = pkA >> 14;
        int cB = pkB & 16383, ttB = pkB >> 14;
        ushort4 hA = hw4[cA * 64 + eg * 16 + q];
        ushort4 hB = hw4[cB * 64 + eg * 16 + q];
        float wA = wS[w][eg][e], wB = wS[w][eg][e + 1];
        float4 sA = sg4[ttA * 16 + q], sB = sg4[ttB * 16 + q];
        float4 fA = bf4_to_f4(hA), fB = bf4_to_f4(hB);
        accA.x += wA * (sA.x * fA.x); accA.y += wA * (sA.y * fA.y);
        accA.z += wA * (sA.z * fA.z); accA.w += wA * (sA.w * fA.w);
        accB.x += wB * (sB.x * fB.x); accB.y += wB * (sB.y * fB.y);
        accB.z += wB * (sB.z * fB.z); accB.w += wB * (sB.w * fB.w);
    }
    if (e < deg) {
        int pk = pkS[w][e];
        int c = pk & 16383, tt = pk >> 14;
        ushort4 hv = hw4[c * 64 + eg * 16 + q];
        float wv = wS[w][eg][e];
        float4 sv = sg4[tt * 16 + q];
        float4 f = bf4_to_f4(hv);
        accA.x += wv * (sv.x * f.x); accA.y += wv * (sv.y * f.y);
        accA.z += wv * (sv.z * f.z); accA.w += wv * (sv.w * f.w);
    }
    float S0 = wave_reduce_sum(w1.x + w2.x);
    float S1 = wave_reduce_sum(w1.y + w2.y);
    float S2 = wave_reduce_sum(w1.z + w2.z);
    float S3 = wave_reduce_sum(w1.w + w2.w);
    float i0 = (S0 > 0.f) ? 1.f / S0 : 0.f, i1 = (S1 > 0.f) ? 1.f / S1 : 0.f;
    float i2 = (S2 > 0.f) ? 1.f / S2 : 0.f, i3 = (S3 > 0.f) ? 1.f / S3 : 0.f;
    float is = (eg == 0) ? i0 : (eg == 1) ? i1 : (eg == 2) ? i2 : i3;
    float4 o{(accA.x + accB.x) * is, (accA.y + accB.y) * is,
             (accA.z + accB.z) * is, (accA.w + accB.w) * is};
    ((float4*)out)[(eg * NN + n) * 16 + q] = o;
}

// ---- Launch -------------------------------------------------------------
extern "C" void kernel_launch(void* const* d_in, const int* in_sizes, int n_in,
                              void* d_out, int out_size, void* d_ws, size_t ws_size,
                              hipStream_t stream) {
    const float* x     = (const float*)d_in[0];
    const float* ef_in = (const float*)d_in[1];
    const float* theta = (const float*)d_in[2];
    const float* wr    = (const float*)d_in[3];
    const float* we    = (const float*)d_in[4];
    const int* edge_index = (const int*)d_in[5];
    const int* edge_type  = (const int*)d_in[6];
    float* out = (float*)d_out;

    const int* row = edge_index;
    const int* col = edge_index + EE;

    char* p = (char*)d_ws;
    auto alloc = [&](size_t bytes) { void* r = (void*)p; p += (bytes + 255) & ~(size_t)255; return r; };
    int*   cnt     = (int*)  alloc((size_t)NN * 4);
    int*   ce_slot = (int*)  alloc((size_t)NN * SLOT * 4);
    float* a4_0    = (float*)alloc((size_t)NN * 4 * 4);
    float* b4_0    = (float*)alloc((size_t)NN * 4 * 4);
    float* a4_1    = (float*)alloc((size_t)NN * 4 * 4);
    float* b4_1    = (float*)alloc((size_t)NN * 4 * 4);
    unsigned short* hw0 = (unsigned short*)alloc((size_t)NN * DD * 2);
    unsigned short* hw1 = (unsigned short*)alloc((size_t)TT * NN * DD * 2);
    unsigned short* h1  = (unsigned short*)alloc((size_t)TT * NN * DD * 2);
    float* sg      = (float*)alloc((size_t)2 * TT * DD * 4);
    float* rg      = (float*)alloc((size_t)2 * 16 * 4);

    hipMemsetAsync(cnt, 0, (size_t)NN * 4, stream);
    build_node0_kernel<<<HB + NB + 1, 256, 0, stream>>>(
        row, col, edge_type, cnt, ce_slot, x, theta, we, ef_in, wr,
        a4_0, b4_0, hw0, sg, rg);
    edge_agg0_kernel<<<NN / 4, 256, 0, stream>>>(
        cnt, ce_slot, a4_0, b4_0, rg, sg, hw0, h1);
    node1_kernel<<<dim3(NN / 64, TT), 256, 0, stream>>>(
        h1, theta, we, a4_1, b4_1, hw1);
    edge_agg1_kernel<<<NN / 4, 256, 0, stream>>>(
        cnt, ce_slot, a4_1, b4_1, rg + 16, sg + TT * DD, hw1, out);
}

// Round 12
// 142.758 us; speedup vs baseline: 1.0161x; 1.0161x over previous
//
#include <hip/hip_runtime.h>

#define NN 16384
#define EE 262144
#define TT 4
#define DD 64
#define SLOT 96          // slots per node; P(deg>96)~e^-100 for Poisson(16)
#define HB (EE / 256)    // edge-build blocks
#define NB (NN / 64)     // node0 tile blocks
#define WPAD 100         // padded edge-table stride (100 % 32 == 4 -> conflict-free)

__device__ inline float wave_reduce_sum(float v) {
    #pragma unroll
    for (int off = 32; off >= 1; off >>= 1) v += __shfl_xor(v, off);
    return v;
}
// reduce float4 across the 4 edge-groups (lanes L, L^16, L^32, L^48)
__device__ inline float4 edge_group_reduce(float4 v) {
    #pragma unroll
    for (int off = 16; off < 64; off <<= 1) {
        v.x += __shfl_xor(v.x, off); v.y += __shfl_xor(v.y, off);
        v.z += __shfl_xor(v.z, off); v.w += __shfl_xor(v.w, off);
    }
    return v;
}
__device__ inline unsigned short f2bf(float f) {   // RNE
    unsigned u = __float_as_uint(f);
    u += 0x7FFFu + ((u >> 16) & 1u);
    return (unsigned short)(u >> 16);
}
__device__ inline float bf2f(unsigned short h) {
    return __uint_as_float(((unsigned)h) << 16);
}
__device__ inline float4 bf4_to_f4(ushort4 h) {
    return float4{bf2f(h.x), bf2f(h.y), bf2f(h.z), bf2f(h.w)};
}
__device__ inline ushort4 f4_to_bf4(float4 f) {
    return ushort4{f2bf(f.x), f2bf(f.y), f2bf(f.z), f2bf(f.w)};
}
// exp with clamp: softmax is shift-invariant; |rp| <~ 10 here so clamp is
// never active in practice, it only guarantees no inf/NaN.
__device__ inline float cexp(float r) {
    return __expf(fminf(fmaxf(r, -60.f), 60.f));
}

// ---- Fused: slot-CSR build + node0 GEMM tiles + small tables ------------
__global__ __launch_bounds__(256) void build_node0_kernel(
        const int* __restrict__ row, const int* __restrict__ col,
        const int* __restrict__ et, int* __restrict__ cnt,
        int* __restrict__ ce_slot,
        const float* __restrict__ x, const float* __restrict__ theta,
        const float* __restrict__ we, const float* __restrict__ ef_in,
        const float* __restrict__ wr,
        float* __restrict__ a4, float* __restrict__ b4,
        unsigned short* __restrict__ hw0,
        float* __restrict__ sg, float* __restrict__ rg) {
    __shared__ float h_lds[64][68];
    __shared__ float4 we_lds[64][16];
    __shared__ float th_lds[4][2][64];
    __shared__ float part_a[64][4][4];
    __shared__ float part_b[64][4][4];
    __shared__ float ef0[TT * DD];
    __shared__ float ef1[TT * DD];
    int tid = threadIdx.x;
    int bid = blockIdx.x;

    if (bid < HB) {                      // ---- hist+scatter in one pass
        int e = bid * 256 + tid;
        int r = row[e];
        int pos = atomicAdd(&cnt[r], 1);
        if (pos < SLOT)                  // clamp: never corrupt memory
            ce_slot[r * SLOT + pos] = col[e] | (et[e] << 14);
        return;
    }
    bid -= HB;

    if (bid == NB) {                     // ---- small tables (both layers)
        int t = tid >> 6, d = tid & 63;
        ef0[tid] = ef_in[tid];
        __syncthreads();
        if (tid < 16) {
            int tt = tid & 3, tq = tid >> 2;
            float s = 0.f;
            for (int k = 0; k < DD; ++k) s += theta[tq * 192 + k] * ef0[tt * DD + k];
            rg[tq * 4 + tt] = s;
        }
        float acc = 0.f;
        for (int k = 0; k < DD; ++k) acc += ef0[t * DD + k] * wr[k * DD + d];
        sg[tid] = 1.f / (1.f + __expf(-acc));
        ef1[tid] = fmaxf(acc, 0.f);
        __syncthreads();
        if (tid < 16) {
            int tt = tid & 3, tq = tid >> 2;
            float s = 0.f;
            for (int k = 0; k < DD; ++k) s += theta[(TT + tq) * 192 + k] * ef1[tt * DD + k];
            rg[16 + tq * 4 + tt] = s;
        }
        float acc2 = 0.f;
        for (int k = 0; k < DD; ++k) acc2 += ef1[t * DD + k] * wr[DD * DD + k * DD + d];
        sg[TT * DD + tid] = 1.f / (1.f + __expf(-acc2));
        return;
    }

    // ---- node0 tile: x@we0 -> hw0 (bf16), packed a4,b4 for all 4 t
    int n0 = bid * 64;
    {
        int q = tid & 15, nr = tid >> 4;
        #pragma unroll
        for (int r = 0; r < 4; ++r) {
            int n = r * 16 + nr;
            *(float4*)&h_lds[n][4 * q] = ((const float4*)x)[(n0 + n) * 16 + q];
        }
    }
    {
        const float4* we4 = (const float4*)we;
        #pragma unroll
        for (int r = 0; r < 4; ++r)
            ((float4*)we_lds)[tid + 256 * r] = we4[tid + 256 * r];
    }
    {
        #pragma unroll
        for (int r = 0; r < 2; ++r) {
            int e = tid + 256 * r;
            int t = e >> 7, ab = (e >> 6) & 1, k = e & 63;
            th_lds[t][ab][k] = theta[t * 192 + 64 + ab * 64 + k];
        }
    }
    __syncthreads();
    int i = tid >> 4, j = tid & 15;
    float4 acc[4];
    acc[0] = acc[1] = acc[2] = acc[3] = float4{0.f, 0.f, 0.f, 0.f};
    for (int k = 0; k < 64; ++k) {
        float4 wv = we_lds[k][j];
        #pragma unroll
        for (int r = 0; r < 4; ++r) {
            float hv = h_lds[4 * i + r][k];
            acc[r].x += hv * wv.x; acc[r].y += hv * wv.y;
            acc[r].z += hv * wv.z; acc[r].w += hv * wv.w;
        }
    }
    {   // a,b partials: thread j -> (t = j>>2, k range [16*(j&3), +16))
        int t = j >> 2, kq = j & 3;
        float pa[4] = {0, 0, 0, 0}, pb[4] = {0, 0, 0, 0};
        for (int kk = 0; kk < 16; ++kk) {
            int k = kq * 16 + kk;
            float ti = th_lds[t][0][k], tj = th_lds[t][1][k];
            #pragma unroll
            for (int r = 0; r < 4; ++r) {
                float hv = h_lds[4 * i + r][k];
                pa[r] += hv * ti; pb[r] += hv * tj;
            }
        }
        #pragma unroll
        for (int r = 0; r < 4; ++r) {
            part_a[4 * i + r][t][kq] = pa[r];
            part_b[4 * i + r][t][kq] = pb[r];
        }
    }
    #pragma unroll
    for (int r = 0; r < 4; ++r)
        ((ushort4*)hw0)[(n0 + 4 * i + r) * 16 + j] = f4_to_bf4(acc[r]);
    __syncthreads();
    {
        int n = tid >> 2, t = tid & 3;
        float4 va = *(float4*)&part_a[n][t][0];
        float4 vb = *(float4*)&part_b[n][t][0];
        a4[(n0 + n) * 4 + t] = va.x + va.y + va.z + va.w;
        b4[(n0 + n) * 4 + t] = vb.x + vb.y + vb.z + vb.w;
    }
}

// ---- Layer-1 node transforms: per-t tiled GEMM relu-free h1(bf16)@we1 ---
// hw1 written INTERLEAVED: [n][t][d] so agg1 reads 512 contiguous B/edge.
__global__ __launch_bounds__(256) void node1_kernel(
        const unsigned short* __restrict__ h1, const float* __restrict__ theta,
        const float* __restrict__ we,
        float* __restrict__ a4, float* __restrict__ b4,
        unsigned short* __restrict__ hw) {
    __shared__ float h_lds[64][68];
    __shared__ float4 we_lds[64][16];
    __shared__ float th_lds[2][64];
    __shared__ float part_a[64][17];
    __shared__ float part_b[64][17];
    int tid = threadIdx.x;
    int t = blockIdx.y;
    int n0 = blockIdx.x * 64;
    const ushort4* ht = (const ushort4*)h1 + (size_t)t * NN * 16;
    {
        int q = tid & 15, nr = tid >> 4;
        #pragma unroll
        for (int r = 0; r < 4; ++r) {
            int n = r * 16 + nr;
            *(float4*)&h_lds[n][4 * q] = bf4_to_f4(ht[(n0 + n) * 16 + q]);
        }
    }
    {
        const float4* we4 = (const float4*)(we + DD * DD);
        #pragma unroll
        for (int r = 0; r < 4; ++r)
            ((float4*)we_lds)[tid + 256 * r] = we4[tid + 256 * r];
    }
    if (tid < 128) {
        int ab = tid >> 6, k = tid & 63;
        th_lds[ab][k] = theta[(TT + t) * 192 + 64 + ab * 64 + k];
    }
    __syncthreads();
    int i = tid >> 4, j = tid & 15;
    float4 acc[4];
    acc[0] = acc[1] = acc[2] = acc[3] = float4{0.f, 0.f, 0.f, 0.f};
    for (int k = 0; k < 64; ++k) {
        float4 wv = we_lds[k][j];
        #pragma unroll
        for (int r = 0; r < 4; ++r) {
            float hv = h_lds[4 * i + r][k];
            acc[r].x += hv * wv.x; acc[r].y += hv * wv.y;
            acc[r].z += hv * wv.z; acc[r].w += hv * wv.w;
        }
    }
    {   // a,b partials: thread j covers k in [4j, 4j+4)
        float pa[4] = {0, 0, 0, 0}, pb[4] = {0, 0, 0, 0};
        #pragma unroll
        for (int kk = 0; kk < 4; ++kk) {
            int k = 4 * j + kk;
            float ti = th_lds[0][k], tj = th_lds[1][k];
            #pragma unroll
            for (int r = 0; r < 4; ++r) {
                float hv = h_lds[4 * i + r][k];
                pa[r] += hv * ti; pb[r] += hv * tj;
            }
        }
        #pragma unroll
        for (int r = 0; r < 4; ++r) {
            part_a[4 * i + r][j] = pa[r];
            part_b[4 * i + r][j] = pb[r];
        }
    }
    #pragma unroll
    for (int r = 0; r < 4; ++r)
        ((ushort4*)hw)[(size_t)(n0 + 4 * i + r) * 64 + t * 16 + j] = f4_to_bf4(acc[r]);
    __syncthreads();
    if (tid < 64) {
        float s = 0.f;
        #pragma unroll
        for (int jj = 0; jj < 16; ++jj) s += part_a[tid][jj];
        a4[(n0 + tid) * 4 + t] = s;
    } else if (tid < 128) {
        int n = tid - 64;
        float s = 0.f;
        #pragma unroll
        for (int jj = 0; jj < 16; ++jj) s += part_b[n][jj];
        b4[(n0 + n) * 4 + t] = s;
    }
}

// ---- Layer-0 edge agg: no-max softmax, SoA LDS broadcast tables ---------
__global__ __launch_bounds__(256) void edge_agg0_kernel(
        const int* __restrict__ cnt, const int* __restrict__ ce_slot,
        const float* __restrict__ a4, const float* __restrict__ b4,
        const float* __restrict__ rg, const float* __restrict__ sg,
        const unsigned short* __restrict__ hw0, unsigned short* __restrict__ h1) {
    __shared__ float4 sg4[64];
    __shared__ float4 rg4[4];
    __shared__ int   pkS[4][WPAD];
    __shared__ float wS[4][4][WPAD];
    int tid = threadIdx.x;
    if (tid < 64) sg4[tid] = ((const float4*)sg)[tid];
    if (tid < 4)  rg4[tid] = float4{rg[tid], rg[4 + tid], rg[8 + tid], rg[12 + tid]};
    int w = tid >> 6, lane = tid & 63;
    int n = blockIdx.x * 4 + w;
    int deg = cnt[n]; if (deg > SLOT) deg = SLOT;
    const int* ces = ce_slot + n * SLOT;
    float4 av = ((const float4*)a4)[n];
    __syncthreads();

    // Phase A: lane-per-edge, unnormalized exp weights (no max reduction)
    bool ok1 = lane < deg;
    int pk1 = ok1 ? ces[lane] : 0;
    int c1 = pk1 & 16383, tt1 = pk1 >> 14;
    float4 bv = ((const float4*)b4)[c1];
    float4 rv = rg4[tt1];
    float4 w1;
    w1.x = ok1 ? cexp(av.x + bv.x + rv.x) : 0.f;
    w1.y = ok1 ? cexp(av.y + bv.y + rv.y) : 0.f;
    w1.z = ok1 ? cexp(av.z + bv.z + rv.z) : 0.f;
    w1.w = ok1 ? cexp(av.w + bv.w + rv.w) : 0.f;
    pkS[w][lane] = pk1;
    wS[w][0][lane] = w1.x; wS[w][1][lane] = w1.y;
    wS[w][2][lane] = w1.z; wS[w][3][lane] = w1.w;
    float4 w2{0.f, 0.f, 0.f, 0.f};
    if (deg > 64) {                      // wave-uniform, ~never taken
        bool ok2 = lane + 64 < deg;
        int pk2 = ok2 ? ces[lane + 64] : 0;
        int c2 = pk2 & 16383, tt2 = pk2 >> 14;
        float4 bv2 = ((const float4*)b4)[c2];
        float4 rv2 = rg4[tt2];
        w2.x = ok2 ? cexp(av.x + bv2.x + rv2.x) : 0.f;
        w2.y = ok2 ? cexp(av.y + bv2.y + rv2.y) : 0.f;
        w2.z = ok2 ? cexp(av.z + bv2.z + rv2.z) : 0.f;
        w2.w = ok2 ? cexp(av.w + bv2.w + rv2.w) : 0.f;
        if (lane < WPAD - 64) {          // fill 64..99 (incl. zero pad)
            pkS[w][64 + lane] = pk2;
            wS[w][0][64 + lane] = w2.x; wS[w][1][64 + lane] = w2.y;
            wS[w][2][64 + lane] = w2.z; wS[w][3][64 + lane] = w2.w;
        }
    }
    // same-wave LDS write->read: no barrier needed

    // Phase B: 4 edge-groups x 16 lanes; ONE gather per edge serves 4 t
    int eg = lane >> 4, q = lane & 15;
    float4 acc0{0,0,0,0}, acc1{0,0,0,0}, acc2{0,0,0,0}, acc3{0,0,0,0};
    const ushort4* hw4 = (const ushort4*)hw0;
    for (int base = 0; base < deg; base += 4) {
        int e = base + eg;               // e>=deg entries have w==0
        int pk = pkS[w][e];
        int c = pk & 16383, tt = pk >> 14;
        ushort4 hv = hw4[c * 16 + q];
        float4 sgv = sg4[tt * 16 + q];
        float we0 = wS[w][0][e], we1 = wS[w][1][e];
        float we2 = wS[w][2][e], we3 = wS[w][3][e];
        float4 f = bf4_to_f4(hv);
        float4 g{sgv.x * f.x, sgv.y * f.y, sgv.z * f.z, sgv.w * f.w};
        acc0.x += we0 * g.x; acc0.y += we0 * g.y; acc0.z += we0 * g.z; acc0.w += we0 * g.w;
        acc1.x += we1 * g.x; acc1.y += we1 * g.y; acc1.z += we1 * g.z; acc1.w += we1 * g.w;
        acc2.x += we2 * g.x; acc2.y += we2 * g.y; acc2.z += we2 * g.z; acc2.w += we2 * g.w;
        acc3.x += we3 * g.x; acc3.y += we3 * g.y; acc3.z += we3 * g.z; acc3.w += we3 * g.w;
    }
    // S-reduction deferred until after the gather loop (off critical path)
    float S0 = wave_reduce_sum(w1.x + w2.x);
    float S1 = wave_reduce_sum(w1.y + w2.y);
    float S2 = wave_reduce_sum(w1.z + w2.z);
    float S3 = wave_reduce_sum(w1.w + w2.w);
    float i0 = (S0 > 0.f) ? 1.f / S0 : 0.f, i1 = (S1 > 0.f) ? 1.f / S1 : 0.f;
    float i2 = (S2 > 0.f) ? 1.f / S2 : 0.f, i3 = (S3 > 0.f) ? 1.f / S3 : 0.f;
    acc0 = edge_group_reduce(acc0);
    acc1 = edge_group_reduce(acc1);
    acc2 = edge_group_reduce(acc2);
    acc3 = edge_group_reduce(acc3);
    float4 o = acc0;
    if (eg == 1) o = acc1;
    if (eg == 2) o = acc2;
    if (eg == 3) o = acc3;
    float is = (eg == 0) ? i0 : (eg == 1) ? i1 : (eg == 2) ? i2 : i3;
    o.x = fmaxf(o.x * is, 0.f); o.y = fmaxf(o.y * is, 0.f);
    o.z = fmaxf(o.z * is, 0.f); o.w = fmaxf(o.w * is, 0.f);
    ((ushort4*)h1)[(eg * NN + n) * 16 + q] = f4_to_bf4(o);   // bf16 h1
}

// ---- Layer-1 edge agg: group-per-t-plane, 512B contiguous per edge ------
__global__ __launch_bounds__(256) void edge_agg1_kernel(
        const int* __restrict__ cnt, const int* __restrict__ ce_slot,
        const float* __restrict__ a4, const float* __restrict__ b4,
        const float* __restrict__ rg, const float* __restrict__ sg,
        const unsigned short* __restrict__ hw, float* __restrict__ out) {
    __shared__ float4 sg4[64];
    __shared__ float4 rg4[4];
    __shared__ int   pkS[4][WPAD];
    __shared__ float wS[4][4][WPAD];
    int tid = threadIdx.x;
    if (tid < 64) sg4[tid] = ((const float4*)sg)[tid];
    if (tid < 4)  rg4[tid] = float4{rg[tid], rg[4 + tid], rg[8 + tid], rg[12 + tid]};
    int w = tid >> 6, lane = tid & 63;
    int n = blockIdx.x * 4 + w;
    int deg = cnt[n]; if (deg > SLOT) deg = SLOT;
    const int* ces = ce_slot + n * SLOT;
    float4 av = ((const float4*)a4)[n];
    __syncthreads();

    // Phase A (identical to agg0)
    bool ok1 = lane < deg;
    int pk1 = ok1 ? ces[lane] : 0;
    int c1 = pk1 & 16383, tt1 = pk1 >> 14;
    float4 bv = ((const float4*)b4)[c1];
    float4 rv = rg4[tt1];
    float4 w1;
    w1.x = ok1 ? cexp(av.x + bv.x + rv.x) : 0.f;
    w1.y = ok1 ? cexp(av.y + bv.y + rv.y) : 0.f;
    w1.z = ok1 ? cexp(av.z + bv.z + rv.z) : 0.f;
    w1.w = ok1 ? cexp(av.w + bv.w + rv.w) : 0.f;
    pkS[w][lane] = pk1;
    wS[w][0][lane] = w1.x; wS[w][1][lane] = w1.y;
    wS[w][2][lane] = w1.z; wS[w][3][lane] = w1.w;
    float4 w2{0.f, 0.f, 0.f, 0.f};
    if (deg > 64) {                      // wave-uniform, ~never taken
        bool ok2 = lane + 64 < deg;
        int pk2 = ok2 ? ces[lane + 64] : 0;
        int c2 = pk2 & 16383, tt2 = pk2 >> 14;
        float4 bv2 = ((const float4*)b4)[c2];
        float4 rv2 = rg4[tt2];
        w2.x = ok2 ? cexp(av.x + bv2.x + rv2.x) : 0.f;
        w2.y = ok2 ? cexp(av.y + bv2.y + rv2.y) : 0.f;
        w2.z = ok2 ? cexp(av.z + bv2.z + rv2.z) : 0.f;
        w2.w = ok2 ? cexp(av.w + bv2.w + rv2.w) : 0.f;
        if (lane < WPAD - 64) {
            pkS[w][64 + lane] = pk2;
            wS[w][0][64 + lane] = w2.x; wS[w][1][64 + lane] = w2.y;
            wS[w][2][64 + lane] = w2.z; wS[w][3][64 + lane] = w2.w;
        }
    }

    // Phase B: group eg owns t-plane eg; wave reads 512 contiguous B/edge.
    // Each lane's acc is final for (t=eg, dims 4q..4q+3) -> no reduce.
    int eg = lane >> 4, q = lane & 15;
    float4 acc{0, 0, 0, 0};
    const ushort4* hw4 = (const ushort4*)hw;
    for (int e = 0; e < deg; ++e) {
        int pk = pkS[w][e];              // uniform addr -> broadcast
        int c = pk & 16383, tt = pk >> 14;
        ushort4 hv = hw4[c * 64 + eg * 16 + q];
        float4 sgv = sg4[tt * 16 + q];
        float wv = wS[w][eg][e];
        float4 f = bf4_to_f4(hv);
        acc.x += wv * (sgv.x * f.x); acc.y += wv * (sgv.y * f.y);
        acc.z += wv * (sgv.z * f.z); acc.w += wv * (sgv.w * f.w);
    }
    float S0 = wave_reduce_sum(w1.x + w2.x);
    float S1 = wave_reduce_sum(w1.y + w2.y);
    float S2 = wave_reduce_sum(w1.z + w2.z);
    float S3 = wave_reduce_sum(w1.w + w2.w);
    float i0 = (S0 > 0.f) ? 1.f / S0 : 0.f, i1 = (S1 > 0.f) ? 1.f / S1 : 0.f;
    float i2 = (S2 > 0.f) ? 1.f / S2 : 0.f, i3 = (S3 > 0.f) ? 1.f / S3 : 0.f;
    float is = (eg == 0) ? i0 : (eg == 1) ? i1 : (eg == 2) ? i2 : i3;
    acc.x *= is; acc.y *= is; acc.z *= is; acc.w *= is;
    ((float4*)out)[(eg * NN + n) * 16 + q] = acc;
}

// ---- Launch -------------------------------------------------------------
extern "C" void kernel_launch(void* const* d_in, const int* in_sizes, int n_in,
                              void* d_out, int out_size, void* d_ws, size_t ws_size,
                              hipStream_t stream) {
    const float* x     = (const float*)d_in[0];
    const float* ef_in = (const float*)d_in[1];
    const float* theta = (const float*)d_in[2];
    const float* wr    = (const float*)d_in[3];
    const float* we    = (const float*)d_in[4];
    const int* edge_index = (const int*)d_in[5];
    const int* edge_type  = (const int*)d_in[6];
    float* out = (float*)d_out;

    const int* row = edge_index;
    const int* col = edge_index + EE;

    char* p = (char*)d_ws;
    auto alloc = [&](size_t bytes) { void* r = (void*)p; p += (bytes + 255) & ~(size_t)255; return r; };
    int*   cnt     = (int*)  alloc((size_t)NN * 4);
    int*   ce_slot = (int*)  alloc((size_t)NN * SLOT * 4);
    float* a4_0    = (float*)alloc((size_t)NN * 4 * 4);
    float* b4_0    = (float*)alloc((size_t)NN * 4 * 4);
    float* a4_1    = (float*)alloc((size_t)NN * 4 * 4);
    float* b4_1    = (float*)alloc((size_t)NN * 4 * 4);
    unsigned short* hw0 = (unsigned short*)alloc((size_t)NN * DD * 2);
    unsigned short* hw1 = (unsigned short*)alloc((size_t)TT * NN * DD * 2);
    unsigned short* h1  = (unsigned short*)alloc((size_t)TT * NN * DD * 2);
    float* sg      = (float*)alloc((size_t)2 * TT * DD * 4);
    float* rg      = (float*)alloc((size_t)2 * 16 * 4);

    hipMemsetAsync(cnt, 0, (size_t)NN * 4, stream);
    build_node0_kernel<<<HB + NB + 1, 256, 0, stream>>>(
        row, col, edge_type, cnt, ce_slot, x, theta, we, ef_in, wr,
        a4_0, b4_0, hw0, sg, rg);
    edge_agg0_kernel<<<NN / 4, 256, 0, stream>>>(
        cnt, ce_slot, a4_0, b4_0, rg, sg, hw0, h1);
    node1_kernel<<<dim3(NN / 64, TT), 256, 0, stream>>>(
        h1, theta, we, a4_1, b4_1, hw1);
    edge_agg1_kernel<<<NN / 4, 256, 0, stream>>>(
        cnt, ce_slot, a4_1, b4_1, rg + 16, sg + TT * DD, hw1, out);
}